// Round 1
// 276.892 us; speedup vs baseline: 1.0829x; 1.0829x over previous
//
#include <hip/hip_runtime.h>
#include <math.h>

// ---------------------------------------------------------------------------
// QASS Multihead Attention, MI355X (gfx950)
// B=2, N=2048, D=1024, H=16, Dh=64, HID=64. Output fp32 [B,N,D].
//
// R7: k_attn reworked to 256 q-rows/block (4 rg per wave, processed in two
//     pairs to bound VGPRs): halves per-tile fixed costs (barrier, DMA
//     traffic, K/V fragment re-reads) per MFMA; grid 512 = exactly 2
//     blocks/CU, single batch; s_setprio(1) around MFMA clusters.
// Precision: fp16 projections/QK^T, bf16 P*V and O-partials, fp32 softmax
// (deferred, log2 domain; exp2 never overflows fp32).
// ---------------------------------------------------------------------------

typedef _Float16 half_t;
using half8   = __attribute__((ext_vector_type(8))) _Float16;  // 4 VGPRs
using bhalf8  = __attribute__((ext_vector_type(8))) short;     // 8 bf16
using floatx4 = __attribute__((ext_vector_type(4))) float;     // MFMA C/D

__device__ inline unsigned short f2bf(float f) {
  union { float f; unsigned int u; } v; v.f = f;
  unsigned int u = v.u;
  u = u + 0x7fffu + ((u >> 16) & 1u);
  return (unsigned short)(u >> 16);
}
__device__ inline float bf2f(unsigned short h) {
  union { unsigned int u; float f; } v; v.u = ((unsigned int)h) << 16;
  return v.f;
}
__device__ inline float gelu_f(float x) {      // exact (erf) GELU
  return 0.5f * x * (1.0f + erff(x * 0.70710678118654752440f));
}

#define MFMAF16(a, b, c)  __builtin_amdgcn_mfma_f32_16x16x32_f16((a), (b), (c), 0, 0, 0)
#define MFMABF16(a, b, c) __builtin_amdgcn_mfma_f32_16x16x32_bf16((a), (b), (c), 0, 0, 0)

__device__ __forceinline__ void dma16(const void* g, void* l) {
  __builtin_amdgcn_global_load_lds(
      (const __attribute__((address_space(1))) unsigned int*)g,
      (__attribute__((address_space(3))) unsigned int*)l, 16, 0, 0);
}

// ---------------------------------------------------------------------------
// fp32->fp16 conversion (q/k/v 3x4M + weights 4x1M) and (blocks >= 8192)
// base[1024] = gelu(log(n) * wb1) @ wb2.T
// ---------------------------------------------------------------------------
__global__ __launch_bounds__(256) void k_cvtbase(
    const float* __restrict__ q, const float* __restrict__ k, const float* __restrict__ v,
    const float* __restrict__ wq, const float* __restrict__ wk,
    const float* __restrict__ wv, const float* __restrict__ wo,
    half_t* __restrict__ q16, half_t* __restrict__ k16, half_t* __restrict__ v16,
    half_t* __restrict__ w16,
    const float* __restrict__ wb1, const float* __restrict__ wb2,
    const int* __restrict__ nctx, float* __restrict__ base_out) {
  int tid = threadIdx.x;
  if (blockIdx.x >= 8192) {                    // base path (4 blocks)
    __shared__ float h1[64];
    float logn = logf((float)(*nctx));
    if (tid < 64) h1[tid] = gelu_f(logn * wb1[tid]);
    __syncthreads();
    int i = (blockIdx.x - 8192) * 256 + tid;
    float s = 0.f;
#pragma unroll
    for (int j = 0; j < 64; j++) s += h1[j] * wb2[i * 64 + j];
    base_out[i] = s;
    return;
  }
  size_t e = ((size_t)blockIdx.x * 256 + tid) * 8;
  const float* src; half_t* dst; size_t off;
  if (e < (size_t)3 * 4194304) {
    int t = (int)(e >> 22); off = e & 4194303;
    src = (t == 0) ? q : (t == 1 ? k : v);
    dst = (t == 0) ? q16 : (t == 1 ? k16 : v16);
  } else {
    size_t e2 = e - (size_t)3 * 4194304;
    int t = (int)(e2 >> 20); off = (e2 & 1048575);
    src = (t == 0) ? wq : (t == 1 ? wk : (t == 2 ? wv : wo));
    dst = w16 + (size_t)t * 1048576;
  }
  float4 a = *(const float4*)(src + off);
  float4 b = *(const float4*)(src + off + 4);
  half8 h;
  h[0] = (half_t)a.x; h[1] = (half_t)a.y; h[2] = (half_t)a.z; h[3] = (half_t)a.w;
  h[4] = (half_t)b.x; h[5] = (half_t)b.y; h[6] = (half_t)b.z; h[7] = (half_t)b.w;
  *(half8*)(dst + off) = h;
}

// ---------------------------------------------------------------------------
// fp16 GEMM  C[4096,1024] = A @ W^T, 128x128 tile, BK=64, 4 waves (2x2),
// each wave 64x64 (4x4 frags). global_load_lds staging, XOR chunk swizzle.
// MODE 0 (QKV, grid.z selects): z=0 -> qp16 [B,H,N,Dh] fp16
//                               z=1 -> kswz fp16 (chunk-swizzled d)
//                               z=2 -> vtl bf16 tiles (pos-swizzled)
// MODE 3: A=obf fp16 [4096,1024], -> fp32 out
// ---------------------------------------------------------------------------
template <int MODE>
__global__ __launch_bounds__(256, 3) void k_gemm(const half_t* __restrict__ Abase,
                                                 const half_t* __restrict__ Wbase,
                                                 half_t* __restrict__ qp16,
                                                 half_t* __restrict__ kswz,
                                                 unsigned short* __restrict__ vtl,
                                                 float* __restrict__ outf) {
  const int z = (MODE == 0) ? blockIdx.z : 0;
  const half_t* Ag = Abase + (size_t)z * 4194304;
  const half_t* Wg = Wbase + (size_t)z * 1048576;
  __shared__ __align__(16) half_t As[128 * 64];   // 16 KB
  __shared__ __align__(16) half_t Bs[128 * 64];   // 16 KB
  const int tid = threadIdx.x, lane = tid & 63, w = tid >> 6;
  const int quad = lane >> 4, lm = lane & 15, a7 = lm & 7;
  const int wm = w >> 1, wn = w & 1;
  const int bm0 = blockIdx.y * 128, bn0 = blockIdx.x * 128;

  const floatx4 zero4 = {0.f, 0.f, 0.f, 0.f};
  floatx4 acc[4][4];
#pragma unroll
  for (int i = 0; i < 4; i++)
#pragma unroll
    for (int j = 0; j < 4; j++) acc[i][j] = zero4;

  for (int kk = 0; kk < 1024; kk += 64) {
    __syncthreads();
#pragma unroll
    for (int i = 0; i < 4; i++) {
      int tr = w * 32 + i * 8 + (lane >> 3);
      int c = (lane & 7) ^ (tr & 7);
      dma16((const char*)Ag + ((size_t)(bm0 + tr) * 1024 + kk + c * 8) * 2,
            (char*)As + (w * 32 + i * 8) * 128);
      dma16((const char*)Wg + ((size_t)(bn0 + tr) * 1024 + kk + c * 8) * 2,
            (char*)Bs + (w * 32 + i * 8) * 128);
    }
    __syncthreads();                 // barrier drains vmcnt -> DMA complete

#pragma unroll
    for (int kc = 0; kc < 2; kc++) {
      half8 af[4], bf[4];
#pragma unroll
      for (int tm = 0; tm < 4; tm++)
        af[tm] = *(const half8*)&As[(wm * 64 + tm * 16 + lm) * 64
                                    + (((kc * 4 + quad) ^ a7) << 3)];
#pragma unroll
      for (int tn = 0; tn < 4; tn++)
        bf[tn] = *(const half8*)&Bs[(wn * 64 + tn * 16 + lm) * 64
                                    + (((kc * 4 + quad) ^ a7) << 3)];
#pragma unroll
      for (int tm = 0; tm < 4; tm++)
#pragma unroll
        for (int tn = 0; tn < 4; tn++)
          acc[tm][tn] = MFMAF16(af[tm], bf[tn], acc[tm][tn]);
    }
  }

  // epilogue: C row = quad*4+rr, col = lm
#pragma unroll
  for (int tm = 0; tm < 4; tm++)
#pragma unroll
    for (int tn = 0; tn < 4; tn++)
#pragma unroll
      for (int rr = 0; rr < 4; rr++) {
        int gm = bm0 + wm * 64 + tm * 16 + quad * 4 + rr;   // b*2048+n
        int gn = bn0 + wn * 64 + tn * 16 + lm;              // h*64+d
        float v = acc[tm][tn][rr];
        if constexpr (MODE == 3) {
          outf[(size_t)gm * 1024 + gn] = v;
        } else {
          int b = gm >> 11, n = gm & 2047, hd = gn >> 6, d = gn & 63;
          if (z == 0) {
            qp16[((size_t)((b << 4) + hd) * 2048 + n) * 64 + d] = (half_t)v;
          } else if (z == 1) {
            size_t rowb = ((size_t)((b << 4) + hd) * 2048 + n) * 64;
            kswz[rowb + (size_t)((((d >> 3) ^ (n & 7)) << 3) | (d & 7))] = (half_t)v;
          } else {
            int t = n >> 6, nn = n & 63;
            int pos = ((nn & 15) << 2) | ((nn >> 4) & 3);
            size_t idx = ((size_t)(((b << 4) + hd) * 32 + t) * 64 + d) * 64
                       + (size_t)((((pos >> 3) ^ (d & 7)) * 8) + (pos & 7));
            vtl[idx] = f2bf(v);
          }
        }
      }
}

// ---------------------------------------------------------------------------
// Gate MLP via fp16 MFMA. 256 rows/block (4 waves x 4 tiles of 16 rows).
// h = gelu(q @ wg1^T)  [LDS C->A round-trip]  t = h @ wg2^T,
// qs = q * base * (1+tanh(t)) * (1/8)*log2(e), fp16.
// ---------------------------------------------------------------------------
__global__ __launch_bounds__(256) void k_gate(const half_t* __restrict__ qp,
                                              const float* __restrict__ base_v,
                                              const float* __restrict__ wg1,
                                              const float* __restrict__ wg2,
                                              half_t* __restrict__ qs) {
  __shared__ __align__(16) half_t W1[64 * 72];
  __shared__ __align__(16) half_t W2[64 * 72];
  __shared__ __align__(16) half_t HT[4][16 * 72];
  const int tid = threadIdx.x, lane = tid & 63, w = tid >> 6;
  const int quad = lane >> 4, lm = lane & 15;
  for (int i = tid; i < 4096; i += 256) {
    int j = i >> 6, d = i & 63;
    W1[j * 72 + d] = (half_t)wg1[i];
    W2[j * 72 + d] = (half_t)wg2[i];
  }
  __syncthreads();
  const int R0 = blockIdx.x * 256;
  const int hd = (R0 >> 11) & 15;
  float bsev[4];
#pragma unroll
  for (int tn = 0; tn < 4; tn++) bsev[tn] = base_v[hd * 64 + tn * 16 + lm];
  const float cs = 0.18033688011112042f;       // (1/8)*log2(e)
  const floatx4 zero4 = {0.f, 0.f, 0.f, 0.f};
  half_t* ht = HT[w];

  for (int ti = 0; ti < 4; ti++) {
    int r0 = R0 + w * 64 + ti * 16;
    half8 aq0 = *(const half8*)&qp[(size_t)(r0 + lm) * 64 + quad * 8];
    half8 aq1 = *(const half8*)&qp[(size_t)(r0 + lm) * 64 + 32 + quad * 8];
    floatx4 hc[4];
#pragma unroll
    for (int tn = 0; tn < 4; tn++) {
      half8 b0 = *(const half8*)&W1[(tn * 16 + lm) * 72 + quad * 8];
      half8 b1 = *(const half8*)&W1[(tn * 16 + lm) * 72 + 32 + quad * 8];
      floatx4 t = zero4;
      t = MFMAF16(aq0, b0, t);
      t = MFMAF16(aq1, b1, t);
      hc[tn] = t;
    }
#pragma unroll
    for (int tn = 0; tn < 4; tn++)
#pragma unroll
      for (int rr = 0; rr < 4; rr++)
        ht[(quad * 4 + rr) * 72 + tn * 16 + lm] = (half_t)gelu_f(hc[tn][rr]);
    // layer 2 (A-frags from per-wave LDS; in-order LDS per wave)
    half8 ah0 = *(const half8*)&ht[lm * 72 + quad * 8];
    half8 ah1 = *(const half8*)&ht[lm * 72 + 32 + quad * 8];
#pragma unroll
    for (int tn = 0; tn < 4; tn++) {
      half8 b0 = *(const half8*)&W2[(tn * 16 + lm) * 72 + quad * 8];
      half8 b1 = *(const half8*)&W2[(tn * 16 + lm) * 72 + 32 + quad * 8];
      floatx4 t = zero4;
      t = MFMAF16(ah0, b0, t);
      t = MFMAF16(ah1, b1, t);
#pragma unroll
      for (int rr = 0; rr < 4; rr++) {
        int row = r0 + quad * 4 + rr;
        int d = tn * 16 + lm;
        float qv = (float)qp[(size_t)row * 64 + d];
        float g = 1.0f + tanhf(t[rr]);
        qs[(size_t)row * 64 + d] = (half_t)(qv * bsev[tn] * g * cs);
      }
    }
  }
}

// ---------------------------------------------------------------------------
// Flash attention, deferred softmax, key-split x2. Grid (16 hd, 8 qg x 2
// half, 2 b) = 512 blocks -> exactly 2 blocks/CU, one batch; same-head
// blocks pinned to one XCD (linear id step 16 == 0 mod 8).
// Each block: 256 q-rows x 1024 keys (16 tiles). Per wave: 64 q-rows (4 rg,
// processed as 2 pairs to bound live VGPRs). K/V fragments reused across a
// pair -> per-MFMA LDS traffic and per-tile fixed costs (barrier, DMA)
// halve vs the 128-row version. bf16 O-partials + fp32 rsum, combine kernel.
// ---------------------------------------------------------------------------
__global__ __launch_bounds__(256, 2) void k_attn(const half_t* __restrict__ qs,
                                                 const half_t* __restrict__ kswz,
                                                 const unsigned short* __restrict__ vtl,
                                                 unsigned short* __restrict__ Opart,
                                                 float* __restrict__ rpart) {
  __shared__ __align__(16) half_t KH[2][64 * 64];           // 2 x 8 KB
  __shared__ __align__(16) unsigned short VT[2][64 * 64];   // 2 x 8 KB
  constexpr int PS = 68;
  __shared__ __align__(16) unsigned short PL[4][16 * PS];   // 8.5 KB

  const int tid = threadIdx.x;
  const int lane = tid & 63;
  const int w = tid >> 6;
  const int quad = lane >> 4;
  const int lm = lane & 15;
  const int a7 = lm & 7;
  const int hd = blockIdx.x;
  const int qg = blockIdx.y >> 1, half = blockIdx.y & 1;
  const int b = blockIdx.z;
  const int bh = b * 16 + hd;
  const size_t hb = (size_t)bh * 2048 * 64;
  const char* khT = (const char*)(kswz + hb);
  const char* vtT = (const char*)(vtl + (size_t)bh * 32 * 4096);

  half8 qh[4][2];
#pragma unroll
  for (int rg = 0; rg < 4; rg++)
#pragma unroll
    for (int kc = 0; kc < 2; kc++)
      qh[rg][kc] = *(const half8*)(qs + hb
          + (size_t)(qg * 256 + w * 64 + rg * 16 + lm) * 64 + kc * 32 + quad * 8);

  const floatx4 zero4 = {0.f, 0.f, 0.f, 0.f};
  floatx4 O[4][4];
#pragma unroll
  for (int rg = 0; rg < 4; rg++)
#pragma unroll
    for (int dt = 0; dt < 4; dt++) O[rg][dt] = zero4;
  float rsum[4][4];
#pragma unroll
  for (int rg = 0; rg < 4; rg++)
#pragma unroll
    for (int rr = 0; rr < 4; rr++) rsum[rg][rr] = 0.f;

  unsigned short* plw = PL[w];
  const int lo16 = lane * 16;
  const size_t g0 = (size_t)half * 16 * 8192;

  // prologue: stage tile 0 of this half
#pragma unroll
  for (int r = 0; r < 2; r++) {
    int sb = (w * 2 + r) * 1024;
    dma16(khT + g0 + sb + lo16, (char*)KH[0] + sb);
    dma16(vtT + g0 + sb + lo16, (char*)VT[0] + sb);
  }

  for (int t = 0; t < 16; t++) {
    const int cur = t & 1;
    __syncthreads();
    if (t < 15) {
      const int nb = cur ^ 1;
      const size_t gof = g0 + (size_t)(t + 1) * 8192;
#pragma unroll
      for (int r = 0; r < 2; r++) {
        int sb = (w * 2 + r) * 1024;
        dma16(khT + gof + sb + lo16, (char*)KH[nb] + sb);
        dma16(vtT + gof + sb + lo16, (char*)VT[nb] + sb);
      }
    }

    const half_t* kh_ = KH[cur];
    const unsigned short* vt_ = VT[cur];

    // V fragments: loaded once per tile, reused by both pairs (32 VGPRs)
    bhalf8 vf[2][4];
#pragma unroll
    for (int kc4 = 0; kc4 < 2; kc4++)
#pragma unroll
      for (int dt = 0; dt < 4; dt++)
        vf[kc4][dt] = *(const bhalf8*)
            &vt_[(dt * 16 + lm) * 64 + (((kc4 * 4 + quad) ^ a7) << 3)];

#pragma unroll
    for (int p = 0; p < 2; p++) {
      floatx4 s[2][4];
#pragma unroll
      for (int ri = 0; ri < 2; ri++)
#pragma unroll
        for (int kb = 0; kb < 4; kb++) s[ri][kb] = zero4;

      __builtin_amdgcn_s_setprio(1);
#pragma unroll
      for (int kb = 0; kb < 4; kb++)
#pragma unroll
        for (int kc = 0; kc < 2; kc++) {
          int addr = (kb * 16 + lm) * 64 + (((kc * 4 + quad) ^ a7) << 3);
          half8 khf = *(const half8*)&kh_[addr];
#pragma unroll
          for (int ri = 0; ri < 2; ri++)
            s[ri][kb] = MFMAF16(qh[p * 2 + ri][kc], khf, s[ri][kb]);
        }
      __builtin_amdgcn_s_setprio(0);

#pragma unroll
      for (int ri = 0; ri < 2; ri++) {
        const int rg = p * 2 + ri;
#pragma unroll
        for (int rr = 0; rr < 4; rr++) {
          float p0 = __builtin_amdgcn_exp2f(s[ri][0][rr]);
          float p1 = __builtin_amdgcn_exp2f(s[ri][1][rr]);
          float p2 = __builtin_amdgcn_exp2f(s[ri][2][rr]);
          float p3 = __builtin_amdgcn_exp2f(s[ri][3][rr]);
          rsum[rg][rr] += (p0 + p1) + (p2 + p3);
          unsigned int u0 = __float_as_uint(p0) + 0x8000u;
          unsigned int u1 = __float_as_uint(p1) + 0x8000u;
          unsigned int u2 = __float_as_uint(p2) + 0x8000u;
          unsigned int u3 = __float_as_uint(p3) + 0x8000u;
          uint2 pk;
          pk.x = __builtin_amdgcn_perm(u1, u0, 0x07060302u);
          pk.y = __builtin_amdgcn_perm(u3, u2, 0x07060302u);
          *(uint2*)&plw[(quad * 4 + rr) * PS + lm * 4] = pk;
        }
        __builtin_amdgcn_s_setprio(1);
#pragma unroll
        for (int kc4 = 0; kc4 < 2; kc4++) {
          bhalf8 pf = *(const bhalf8*)&plw[lm * PS + kc4 * 32 + quad * 8];
#pragma unroll
          for (int dt = 0; dt < 4; dt++)
            O[rg][dt] = MFMABF16(pf, vf[kc4][dt], O[rg][dt]);
        }
        __builtin_amdgcn_s_setprio(0);
      }
    }
  }

  // partial rsum (reduce over lm) and bf16 O-partials
  unsigned short* op = Opart + (size_t)half * 65536 * 64;
  float* rp = rpart + (size_t)half * 65536;
#pragma unroll
  for (int rg = 0; rg < 4; rg++)
#pragma unroll
    for (int rr = 0; rr < 4; rr++) {
      float rs = rsum[rg][rr];
      rs += __shfl_xor(rs, 1, 64);
      rs += __shfl_xor(rs, 2, 64);
      rs += __shfl_xor(rs, 4, 64);
      rs += __shfl_xor(rs, 8, 64);
      int n = qg * 256 + w * 64 + rg * 16 + quad * 4 + rr;
      size_t row = (size_t)bh * 2048 + n;
      if (lm == 0) rp[row] = rs;
#pragma unroll
      for (int dt = 0; dt < 4; dt++)
        op[row * 64 + dt * 16 + lm] = f2bf(O[rg][dt][rr]);
    }
}

// ---------------------------------------------------------------------------
// combine: o = (O0+O1)/(r0+r1) -> obf fp16 [4096,1024] (out-proj A layout)
// ---------------------------------------------------------------------------
__global__ __launch_bounds__(256) void k_combine(const unsigned short* __restrict__ Opart,
                                                 const float* __restrict__ rpart,
                                                 half_t* __restrict__ obf) {
  size_t e = ((size_t)blockIdx.x * 256 + threadIdx.x) * 8;
  size_t row = e >> 6; int d0 = (int)(e & 63);
  float inv = 1.0f / (rpart[row] + rpart[65536 + row]);
  bhalf8 o0 = *(const bhalf8*)&Opart[row * 64 + d0];
  bhalf8 o1 = *(const bhalf8*)&Opart[(size_t)65536 * 64 + row * 64 + d0];
  int b = (int)(row >> 15), h = (int)((row >> 11) & 15), n = (int)(row & 2047);
  half8 o;
#pragma unroll
  for (int j = 0; j < 8; j++)
    o[j] = (half_t)((bf2f((unsigned short)o0[j]) + bf2f((unsigned short)o1[j])) * inv);
  *(half8*)&obf[((size_t)(b * 2048 + n)) * 1024 + h * 64 + d0] = o;
}

// ---------------------------------------------------------------------------
extern "C" void kernel_launch(void* const* d_in, const int* in_sizes, int n_in,
                              void* d_out, int out_size, void* d_ws, size_t ws_size,
                              hipStream_t stream) {
  const float* query = (const float*)d_in[0];
  const float* key_  = (const float*)d_in[1];
  const float* value = (const float*)d_in[2];
  const float* wq  = (const float*)d_in[4];
  const float* wk  = (const float*)d_in[5];
  const float* wv  = (const float*)d_in[6];
  const float* wo  = (const float*)d_in[7];
  const float* wb1 = (const float*)d_in[8];
  const float* wb2 = (const float*)d_in[9];
  const float* wg1 = (const float*)d_in[10];
  const float* wg2 = (const float*)d_in[11];
  const int* nctx  = (const int*)d_in[12];
  float* out = (float*)d_out;

  char* ws = (char*)d_ws;
  size_t o = 0;
  float* base_v = (float*)(ws + o); o += 4096;
  half_t* q16   = (half_t*)(ws + o); o += (size_t)4096 * 1024 * 2;   // later: qs
  half_t* k16   = (half_t*)(ws + o); o += (size_t)4096 * 1024 * 2;   // later: obf
  half_t* v16   = (half_t*)(ws + o); o += (size_t)4096 * 1024 * 2;
  half_t* w16   = (half_t*)(ws + o); o += (size_t)4 * 1024 * 1024 * 2;
  half_t* qp16  = (half_t*)(ws + o); o += (size_t)4096 * 1024 * 2;
  half_t* kswz  = (half_t*)(ws + o); o += (size_t)4096 * 1024 * 2;
  unsigned short* vtl = (unsigned short*)(ws + o); o += (size_t)4096 * 1024 * 2;
  unsigned short* Opart = (unsigned short*)(ws + o); o += (size_t)2 * 65536 * 64 * 2;
  float* rpart = (float*)(ws + o); o += (size_t)2 * 65536 * 4;
  half_t* qs  = q16;    // aliases (q16/k16 dead after k_gemm<0>)
  half_t* obf = k16;

  k_cvtbase<<<8196, 256, 0, stream>>>(query, key_, value, wq, wk, wv, wo,
                                      q16, k16, v16, w16, wb1, wb2, nctx, base_v);
  k_gemm<0><<<dim3(8, 32, 3), 256, 0, stream>>>(q16, w16, qp16, kswz, vtl, nullptr);
  k_gate<<<256, 256, 0, stream>>>(qp16, base_v, wg1, wg2, qs);
  k_attn<<<dim3(16, 16, 2), 256, 0, stream>>>(qs, kswz, vtl, Opart, rpart);
  k_combine<<<2048, 256, 0, stream>>>(Opart, rpart, obf);
  k_gemm<3><<<dim3(8, 32, 1), 256, 0, stream>>>(obf, w16 + (size_t)3 * 1048576,
                                                nullptr, nullptr, nullptr, out);
}